// Round 1
// 516.594 us; speedup vs baseline: 1.0900x; 1.0900x over previous
//
#include <hip/hip_runtime.h>
#include <hip/hip_bf16.h>
#include <cstdint>
#include <cstddef>

#define D_IN  4096
#define D_OUT 4096
#define M_TOK 8192   // 4 * 2048
#define QG    128

typedef __bf16 bf16x8 __attribute__((ext_vector_type(8)));
typedef float  floatx4 __attribute__((ext_vector_type(4)));

// ---------------- scale + reciprocal precompute ----------------
__global__ __launch_bounds__(256) void scale_kernel(const float* __restrict__ ls,
                                                    float* __restrict__ scale,
                                                    float* __restrict__ rinv) {
    int i = blockIdx.x * 256 + threadIdx.x;
    if (i < D_IN) {
        float s = expf(ls[i]);
        s = fminf(fmaxf(s, 1e-4f), 1e4f);
        scale[i] = s;
        rinv[i]  = 1.0f / s;   // correctly-rounded divide, <=1 ulp vs x/s
    }
}

// ---------------- activation fake-quant (per-row symmetric 8-bit) ----------------
__global__ __launch_bounds__(256) void act_quant(const float* __restrict__ x,
                                                 const float* __restrict__ rinv,
                                                 __hip_bfloat16* __restrict__ xq) {
    const int row = blockIdx.x;
    const int tid = threadIdx.x;
    const float4* xr = (const float4*)(x + (size_t)row * D_IN);
    const float4* rv = (const float4*)rinv;

    float v[16];
    float amax = 0.f;
#pragma unroll
    for (int j = 0; j < 4; ++j) {
        int idx = j * 256 + tid;
        float4 xv = xr[idx];
        float4 ri = rv[idx];
        float a = xv.x * ri.x, b = xv.y * ri.y, c = xv.z * ri.z, d = xv.w * ri.w;
        v[j * 4 + 0] = a; v[j * 4 + 1] = b; v[j * 4 + 2] = c; v[j * 4 + 3] = d;
        amax = fmaxf(amax, fmaxf(fmaxf(fabsf(a), fabsf(b)), fmaxf(fabsf(c), fabsf(d))));
    }
#pragma unroll
    for (int off = 32; off > 0; off >>= 1)
        amax = fmaxf(amax, __shfl_xor(amax, off, 64));
    __shared__ float smax[4];
    if ((tid & 63) == 0) smax[tid >> 6] = amax;
    __syncthreads();
    float m = fmaxf(fmaxf(smax[0], smax[1]), fmaxf(smax[2], smax[3]));
    m = fmaxf(m, 1e-5f);
    const float s  = m / 127.0f;
    const float qs = 1.0f / s;

    ushort4* xo = (ushort4*)(xq + (size_t)row * D_IN);
#pragma unroll
    for (int j = 0; j < 4; ++j) {
        union { ushort4 u; __hip_bfloat16 h[4]; } p;
#pragma unroll
        for (int k = 0; k < 4; ++k) {
            float dq = fminf(fmaxf(rintf(v[j * 4 + k] * qs), -128.f), 127.f) * s;
            p.h[k] = __float2bfloat16(dq);
        }
        xo[j * 256 + tid] = p.u;
    }
}

// ---------------- weight fake-quant (per-128-group asymmetric 4-bit) ----------------
__global__ __launch_bounds__(256) void w_quant(const float* __restrict__ wgt,
                                               const float* __restrict__ scale,
                                               __hip_bfloat16* __restrict__ wq) {
    const int wid  = blockIdx.x * 4 + (threadIdx.x >> 6);
    const int lane = threadIdx.x & 63;
    const size_t e0 = (size_t)wid * 256 + lane * 4;
    const int d0 = (int)(e0 & (D_IN - 1));

    float4 wv = *(const float4*)(wgt + e0);
    float4 sv = *(const float4*)(scale + d0);
    float w0 = wv.x * sv.x, w1 = wv.y * sv.y, w2 = wv.z * sv.z, w3 = wv.w * sv.w;

    float mx = fmaxf(fmaxf(w0, w1), fmaxf(w2, w3));
    float mn = fminf(fminf(w0, w1), fminf(w2, w3));
#pragma unroll
    for (int off = 16; off > 0; off >>= 1) {
        mx = fmaxf(mx, __shfl_xor(mx, off, 64));
        mn = fminf(mn, __shfl_xor(mn, off, 64));
    }
    const float s  = fmaxf(mx - mn, 1e-5f) / 15.0f;
    const float rs = 1.0f / s;
    const float z  = fminf(fmaxf(-rintf(mn * rs), 0.f), 15.f);

    union { ushort4 u; __hip_bfloat16 h[4]; } p;
    float wl[4] = {w0, w1, w2, w3};
#pragma unroll
    for (int k = 0; k < 4; ++k) {
        float dq = (fminf(fmaxf(rintf(wl[k] * rs) + z, 0.f), 15.f) - z) * s;
        p.h[k] = __float2bfloat16(dq);
    }
    *(ushort4*)(wq + e0) = p.u;
}

// ---------------- GEMM: C[M,N] = A[M,K] * B[N,K]^T + bias ----------------
// 256x256 tile, BK=64, 8 waves (2M x 4N), 8-phase counted-vmcnt schedule
// (T2+T3+T4+T5 per the 256^2 template, re-derived in plain HIP).
//
// LDS regions (16 KB each, granule = 16 B = 8 bf16):
//   [buf][mat A/B][khalf]  -> offset shorts: buf*32768 + mat*16384 + kh*8192
//   region layout: 256 rows x 4 granules, granule (r,c) holds GLOBAL chunk
//   c ^ ((r>>1)&3)  (source pre-swizzle; LDS dest stays linear for
//   global_load_lds). Read side applies the same involution -> perfect
//   8-way spread over the 128-B bank wrap (0 conflicts).
//
// Phases per K-tile (t): p = (m-fragset, kstep):
//   p0: read Bk0+Ak0(frags m0-3); stage Ak1(t+1)->other buf
//   p1: read Ak0(frags m4-7);     stage Bk1(t+1); vmcnt(8)
//   p2: read Bk1+Ak1(frags m0-3); stage Ak0(t+2)->this buf (k0 dead since p2)
//   p3: read Ak1(frags m4-7);     stage Bk0(t+2); vmcnt(8)
// Each phase: reads+stage -> s_barrier -> lgkmcnt(0) -> setprio(1) ->
// 16 MFMA -> setprio(0) -> [vmcnt] -> s_barrier.  vmcnt(8) keeps 4
// half-tiles (8 loads/wave) in flight across barriers; tail (t>=NT-2)
// degrades to vmcnt(0).
__global__ __launch_bounds__(512, 2) void gemm_bt(const __hip_bfloat16* __restrict__ A,
                                                  const __hip_bfloat16* __restrict__ B,
                                                  const float* __restrict__ bias,
                                                  float* __restrict__ C) {
    constexpr int K  = D_IN;
    constexpr int NT = K / 64;           // 64 K-tiles
    static_assert(NT >= 3, "pipeline needs >=3 tiles");
    __shared__ __align__(16) unsigned short lds[2][2][2][256 * 32];   // 128 KiB

    const int tid  = threadIdx.x;
    const int lane = tid & 63;
    const int w    = tid >> 6;           // 0..7
    const int wm   = w >> 2;             // 0..1
    const int wn   = w & 3;              // 0..3
    const int bn   = blockIdx.x;
    const int bm   = blockIdx.y;
    const int q    = lane >> 4;          // k-quad 0..3
    const int l16  = lane & 15;
    const int cOff = (q ^ ((l16 >> 1) & 3)) * 8;   // swizzled granule col (shorts)

    // staging granule mapping: 2 loads/thread per half-tile (1024 granules)
    const int g0 = tid, g1 = tid + 512;
    const int r0 = g0 >> 2, c0 = (g0 & 3) ^ ((g0 >> 3) & 3);
    const int r1 = g1 >> 2, c1 = (g1 & 3) ^ ((g1 >> 3) & 3);

    const unsigned short* Au = (const unsigned short*)A;
    const unsigned short* Bu = (const unsigned short*)B;
    const unsigned short* sA0 = Au + (size_t)(bm * 256 + r0) * K + c0 * 8;
    const unsigned short* sA1 = Au + (size_t)(bm * 256 + r1) * K + c1 * 8;
    const unsigned short* sB0 = Bu + (size_t)(bn * 256 + r0) * K + c0 * 8;
    const unsigned short* sB1 = Bu + (size_t)(bn * 256 + r1) * K + c1 * 8;

    unsigned short* L    = &lds[0][0][0][0];
    unsigned short* dst0 = L + (size_t)g0 * 8;
    unsigned short* dst1 = L + (size_t)g1 * 8;

    auto stage = [&](const unsigned short* s0, const unsigned short* s1, int regOff) {
        __builtin_amdgcn_global_load_lds(
            (const __attribute__((address_space(1))) void*)s0,
            (__attribute__((address_space(3))) void*)(dst0 + regOff), 16, 0, 0);
        __builtin_amdgcn_global_load_lds(
            (const __attribute__((address_space(1))) void*)s1,
            (__attribute__((address_space(3))) void*)(dst1 + regOff), 16, 0, 0);
    };

    // ---- prologue: Ak0(0),Bk0(0),Ak1(0),Bk1(0),Ak0(1),Bk0(1) ----
    stage(sA0,      sA1,      0);                       // Ak0(0)
    stage(sB0,      sB1,      16384);                   // Bk0(0)
    stage(sA0 + 32, sA1 + 32, 8192);                    // Ak1(0)
    stage(sB0 + 32, sB1 + 32, 16384 + 8192);            // Bk1(0)
    stage(sA0 + 64, sA1 + 64, 32768);                   // Ak0(1)
    stage(sB0 + 64, sB1 + 64, 32768 + 16384);           // Bk0(1)
    asm volatile("s_waitcnt vmcnt(8)" ::: "memory");    // tile-0 k0 halves done
    __builtin_amdgcn_sched_barrier(0);
    __builtin_amdgcn_s_barrier();

    floatx4 acc[8][4] = {};
    const int rowA = wm * 128 + l16;
    const int rowB = wn * 64  + l16;

#pragma unroll 2
    for (int t = 0; t < NT; ++t) {
        const int buf  = (t & 1) * 32768;
        const int bufN = buf ^ 32768;
        const unsigned short* A0 = L + buf;
        const unsigned short* A1 = L + buf + 8192;
        const unsigned short* B0 = L + buf + 16384;
        const unsigned short* B1 = L + buf + 16384 + 8192;
        const bool s01    = (t + 1 < NT);
        const bool s23    = (t + 2 < NT);
        const bool steady = (t < NT - 2);
        const int  k1 = (t + 1) * 64 + 32;   // kh1 of tile t+1
        const int  k2 = (t + 2) * 64;        // kh0 of tile t+2

        bf16x8 af[4], bf[4];

        // ---------- phase 0: m-frags 0..3, kstep 0 ----------
#pragma unroll
        for (int j = 0; j < 4; ++j) bf[j] = *(const bf16x8*)(B0 + (rowB + j * 16) * 32 + cOff);
#pragma unroll
        for (int i = 0; i < 4; ++i) af[i] = *(const bf16x8*)(A0 + (rowA + i * 16) * 32 + cOff);
        if (s01) stage(sA0 + k1, sA1 + k1, bufN + 8192);            // Ak1(t+1)
        __builtin_amdgcn_s_barrier();
        asm volatile("s_waitcnt lgkmcnt(0)" ::: "memory");
        __builtin_amdgcn_sched_barrier(0);
        __builtin_amdgcn_s_setprio(1);
#pragma unroll
        for (int i = 0; i < 4; ++i)
#pragma unroll
            for (int j = 0; j < 4; ++j)
                acc[i][j] = __builtin_amdgcn_mfma_f32_16x16x32_bf16(af[i], bf[j], acc[i][j], 0, 0, 0);
        __builtin_amdgcn_s_setprio(0);
        __builtin_amdgcn_s_barrier();

        // ---------- phase 1: m-frags 4..7, kstep 0 ----------
#pragma unroll
        for (int i = 0; i < 4; ++i) af[i] = *(const bf16x8*)(A0 + (rowA + 64 + i * 16) * 32 + cOff);
        if (s01) stage(sB0 + k1, sB1 + k1, bufN + 16384 + 8192);    // Bk1(t+1)
        __builtin_amdgcn_s_barrier();
        asm volatile("s_waitcnt lgkmcnt(0)" ::: "memory");
        __builtin_amdgcn_sched_barrier(0);
        __builtin_amdgcn_s_setprio(1);
#pragma unroll
        for (int i = 0; i < 4; ++i)
#pragma unroll
            for (int j = 0; j < 4; ++j)
                acc[4 + i][j] = __builtin_amdgcn_mfma_f32_16x16x32_bf16(af[i], bf[j], acc[4 + i][j], 0, 0, 0);
        __builtin_amdgcn_s_setprio(0);
        if (steady) { asm volatile("s_waitcnt vmcnt(8)" ::: "memory"); }
        else        { asm volatile("s_waitcnt vmcnt(0)" ::: "memory"); }
        __builtin_amdgcn_sched_barrier(0);
        __builtin_amdgcn_s_barrier();

        // ---------- phase 2: m-frags 0..3, kstep 1 ----------
#pragma unroll
        for (int j = 0; j < 4; ++j) bf[j] = *(const bf16x8*)(B1 + (rowB + j * 16) * 32 + cOff);
#pragma unroll
        for (int i = 0; i < 4; ++i) af[i] = *(const bf16x8*)(A1 + (rowA + i * 16) * 32 + cOff);
        if (s23) stage(sA0 + k2, sA1 + k2, buf);                    // Ak0(t+2)
        __builtin_amdgcn_s_barrier();
        asm volatile("s_waitcnt lgkmcnt(0)" ::: "memory");
        __builtin_amdgcn_sched_barrier(0);
        __builtin_amdgcn_s_setprio(1);
#pragma unroll
        for (int i = 0; i < 4; ++i)
#pragma unroll
            for (int j = 0; j < 4; ++j)
                acc[i][j] = __builtin_amdgcn_mfma_f32_16x16x32_bf16(af[i], bf[j], acc[i][j], 0, 0, 0);
        __builtin_amdgcn_s_setprio(0);
        __builtin_amdgcn_s_barrier();

        // ---------- phase 3: m-frags 4..7, kstep 1 ----------
#pragma unroll
        for (int i = 0; i < 4; ++i) af[i] = *(const bf16x8*)(A1 + (rowA + 64 + i * 16) * 32 + cOff);
        if (s23) stage(sB0 + k2, sB1 + k2, buf + 16384);            // Bk0(t+2)
        __builtin_amdgcn_s_barrier();
        asm volatile("s_waitcnt lgkmcnt(0)" ::: "memory");
        __builtin_amdgcn_sched_barrier(0);
        __builtin_amdgcn_s_setprio(1);
#pragma unroll
        for (int i = 0; i < 4; ++i)
#pragma unroll
            for (int j = 0; j < 4; ++j)
                acc[4 + i][j] = __builtin_amdgcn_mfma_f32_16x16x32_bf16(af[i], bf[j], acc[4 + i][j], 0, 0, 0);
        __builtin_amdgcn_s_setprio(0);
        if (steady) { asm volatile("s_waitcnt vmcnt(8)" ::: "memory"); }
        else        { asm volatile("s_waitcnt vmcnt(0)" ::: "memory"); }
        __builtin_amdgcn_sched_barrier(0);
        __builtin_amdgcn_s_barrier();
    }

    // ---------------- epilogue: bias + store ----------------
    float bv[4];
#pragma unroll
    for (int j = 0; j < 4; ++j)
        bv[j] = bias[bn * 256 + wn * 64 + j * 16 + l16];

#pragma unroll
    for (int f = 0; f < 8; ++f) {
        int gm = bm * 256 + wm * 128 + f * 16 + q * 4;   // C row = quad*4 + reg
#pragma unroll
        for (int j = 0; j < 4; ++j) {
            int gn = bn * 256 + wn * 64 + j * 16 + l16;  // C col = lane&15
            float* cp = C + (size_t)gm * D_OUT + gn;
#pragma unroll
            for (int r = 0; r < 4; ++r)
                cp[(size_t)r * D_OUT] = acc[f][j][r] + bv[j];
        }
    }
}

extern "C" void kernel_launch(void* const* d_in, const int* in_sizes, int n_in,
                              void* d_out, int out_size, void* d_ws, size_t ws_size,
                              hipStream_t stream) {
    const float* x   = (const float*)d_in[0];
    const float* wgt = (const float*)d_in[1];
    const float* bia = (const float*)d_in[2];
    const float* ls  = (const float*)d_in[3];
    float* out = (float*)d_out;

    char* ws = (char*)d_ws;
    float*          scale = (float*)ws;                                   // 16 KB
    float*          rinv  = (float*)(ws + (16 << 10));                    // 16 KB
    __hip_bfloat16* xq    = (__hip_bfloat16*)(ws + (64 << 10));           // 64 MB
    __hip_bfloat16* wq    = (__hip_bfloat16*)(ws + (64 << 10) + ((size_t)64 << 20)); // 32 MB

    scale_kernel<<<(D_IN + 255) / 256, 256, 0, stream>>>(ls, scale, rinv);
    act_quant<<<M_TOK, 256, 0, stream>>>(x, rinv, xq);
    w_quant<<<(D_OUT * D_IN / 256) / 4, 256, 0, stream>>>(wgt, scale, wq);

    dim3 grid(D_OUT / 256, M_TOK / 256);
    gemm_bt<<<grid, 512, 0, stream>>>(xq, wq, bia, out);
}

// Round 3
// 491.103 us; speedup vs baseline: 1.1466x; 1.0519x over previous
//
#include <hip/hip_runtime.h>
#include <hip/hip_bf16.h>
#include <cstdint>
#include <cstddef>

#define D_IN  4096
#define D_OUT 4096
#define M_TOK 8192   // 4 * 2048
#define QG    128

typedef __bf16 bf16x8 __attribute__((ext_vector_type(8)));
typedef float  floatx4 __attribute__((ext_vector_type(4)));

// ---------------- scale + reciprocal precompute ----------------
__global__ __launch_bounds__(256) void scale_kernel(const float* __restrict__ ls,
                                                    float* __restrict__ scale,
                                                    float* __restrict__ rinv) {
    int i = blockIdx.x * 256 + threadIdx.x;
    if (i < D_IN) {
        float s = expf(ls[i]);
        s = fminf(fmaxf(s, 1e-4f), 1e4f);
        scale[i] = s;
        rinv[i]  = 1.0f / s;   // correctly-rounded divide, <=1 ulp vs x/s
    }
}

// ---------------- activation fake-quant (per-row symmetric 8-bit) ----------------
__global__ __launch_bounds__(256) void act_quant(const float* __restrict__ x,
                                                 const float* __restrict__ rinv,
                                                 __hip_bfloat16* __restrict__ xq) {
    const int row = blockIdx.x;
    const int tid = threadIdx.x;
    const float4* xr = (const float4*)(x + (size_t)row * D_IN);
    const float4* rv = (const float4*)rinv;

    float v[16];
    float amax = 0.f;
#pragma unroll
    for (int j = 0; j < 4; ++j) {
        int idx = j * 256 + tid;
        float4 xv = xr[idx];
        float4 ri = rv[idx];
        float a = xv.x * ri.x, b = xv.y * ri.y, c = xv.z * ri.z, d = xv.w * ri.w;
        v[j * 4 + 0] = a; v[j * 4 + 1] = b; v[j * 4 + 2] = c; v[j * 4 + 3] = d;
        amax = fmaxf(amax, fmaxf(fmaxf(fabsf(a), fabsf(b)), fmaxf(fabsf(c), fabsf(d))));
    }
#pragma unroll
    for (int off = 32; off > 0; off >>= 1)
        amax = fmaxf(amax, __shfl_xor(amax, off, 64));
    __shared__ float smax[4];
    if ((tid & 63) == 0) smax[tid >> 6] = amax;
    __syncthreads();
    float m = fmaxf(fmaxf(smax[0], smax[1]), fmaxf(smax[2], smax[3]));
    m = fmaxf(m, 1e-5f);
    const float s  = m / 127.0f;
    const float qs = 1.0f / s;

    ushort4* xo = (ushort4*)(xq + (size_t)row * D_IN);
#pragma unroll
    for (int j = 0; j < 4; ++j) {
        union { ushort4 u; __hip_bfloat16 h[4]; } p;
#pragma unroll
        for (int k = 0; k < 4; ++k) {
            float dq = fminf(fmaxf(rintf(v[j * 4 + k] * qs), -128.f), 127.f) * s;
            p.h[k] = __float2bfloat16(dq);
        }
        xo[j * 256 + tid] = p.u;
    }
}

// ---------------- weight fake-quant (per-128-group asymmetric 4-bit) ----------------
__global__ __launch_bounds__(256) void w_quant(const float* __restrict__ wgt,
                                               const float* __restrict__ scale,
                                               __hip_bfloat16* __restrict__ wq) {
    const int wid  = blockIdx.x * 4 + (threadIdx.x >> 6);
    const int lane = threadIdx.x & 63;
    const size_t e0 = (size_t)wid * 256 + lane * 4;
    const int d0 = (int)(e0 & (D_IN - 1));

    float4 wv = *(const float4*)(wgt + e0);
    float4 sv = *(const float4*)(scale + d0);
    float w0 = wv.x * sv.x, w1 = wv.y * sv.y, w2 = wv.z * sv.z, w3 = wv.w * sv.w;

    float mx = fmaxf(fmaxf(w0, w1), fmaxf(w2, w3));
    float mn = fminf(fminf(w0, w1), fminf(w2, w3));
#pragma unroll
    for (int off = 16; off > 0; off >>= 1) {
        mx = fmaxf(mx, __shfl_xor(mx, off, 64));
        mn = fminf(mn, __shfl_xor(mn, off, 64));
    }
    const float s  = fmaxf(mx - mn, 1e-5f) / 15.0f;
    const float rs = 1.0f / s;
    const float z  = fminf(fmaxf(-rintf(mn * rs), 0.f), 15.f);

    union { ushort4 u; __hip_bfloat16 h[4]; } p;
    float wl[4] = {w0, w1, w2, w3};
#pragma unroll
    for (int k = 0; k < 4; ++k) {
        float dq = (fminf(fmaxf(rintf(wl[k] * rs) + z, 0.f), 15.f) - z) * s;
        p.h[k] = __float2bfloat16(dq);
    }
    *(ushort4*)(wq + e0) = p.u;
}

// ---------------- GEMM: C[M,N] = A[M,K] * B[N,K]^T + bias ----------------
// 256x256 tile, BK=64, 8 waves (2M x 4N), 4-phase/tile interleave with
// counted vmcnt.  TWO barriers per K-tile (the load-bearing gates that
// carry the vmcnt(8)); all per-phase pacing barriers removed so the 2
// waves/SIMD overlap LDS-read bursts with MFMA clusters.
//
// RESUBMISSION of round-2 source (container-level infra failure, no
// kernel verdict).  Hang audit: all barriers wave-uniform (no divergent
// deadlock); staging addresses in-bounds (k1<=4064, k2<=4032 under
// guards); vmcnt waits cannot hang; race ledger re-verified identical
// to the passing round-1 kernel.
//
// Correctness audit (gate = vmcnt(N) + s_barrier at end of p1 and p3):
//  - every wave retires its own ds_reads via lgkmcnt(0) before its MFMA,
//    which precedes the next gate -> at a gate, ALL waves' reads of the
//    regions re-staged in the following half-tile are retired.
//  - vmcnt(8) at gate G1(t) retires Ak1(t),Bk1(t) (issued t-1 p0/p1),
//    read in p2/p3; G2(t) retires Ak0(t+1),Bk0(t+1), read next tile.
//  - stages between gates target only regions whose last readers
//    retired before the previous gate (verified region-by-region).
//
// LDS regions (16 KB each, granule = 16 B = 8 bf16):
//   [buf][mat A/B][khalf] -> offset shorts: buf*32768 + mat*16384 + kh*8192
//   granule (r,c) holds GLOBAL chunk c ^ ((r>>1)&3) (source pre-swizzle;
//   LDS dest stays linear for global_load_lds; read side applies the same
//   involution) -> 0 bank conflicts (verified: SQ_LDS_BANK_CONFLICT = 0).
__global__ __launch_bounds__(512, 2) void gemm_bt(const __hip_bfloat16* __restrict__ A,
                                                  const __hip_bfloat16* __restrict__ B,
                                                  const float* __restrict__ bias,
                                                  float* __restrict__ C) {
    constexpr int K  = D_IN;
    constexpr int NT = K / 64;           // 64 K-tiles
    static_assert(NT >= 3, "pipeline needs >=3 tiles");
    __shared__ __align__(16) unsigned short lds[2][2][2][256 * 32];   // 128 KiB

    const int tid  = threadIdx.x;
    const int lane = tid & 63;
    const int w    = tid >> 6;           // 0..7
    const int wm   = w >> 2;             // 0..1
    const int wn   = w & 3;              // 0..3
    const int bn   = blockIdx.x;
    const int bm   = blockIdx.y;
    const int q    = lane >> 4;          // k-quad 0..3
    const int l16  = lane & 15;
    const int cOff = (q ^ ((l16 >> 1) & 3)) * 8;   // swizzled granule col (shorts)

    // staging granule mapping: 2 loads/thread per half-tile (1024 granules)
    const int g0 = tid, g1 = tid + 512;
    const int r0 = g0 >> 2, c0 = (g0 & 3) ^ ((g0 >> 3) & 3);
    const int r1 = g1 >> 2, c1 = (g1 & 3) ^ ((g1 >> 3) & 3);

    const unsigned short* Au = (const unsigned short*)A;
    const unsigned short* Bu = (const unsigned short*)B;
    const unsigned short* sA0 = Au + (size_t)(bm * 256 + r0) * K + c0 * 8;
    const unsigned short* sA1 = Au + (size_t)(bm * 256 + r1) * K + c1 * 8;
    const unsigned short* sB0 = Bu + (size_t)(bn * 256 + r0) * K + c0 * 8;
    const unsigned short* sB1 = Bu + (size_t)(bn * 256 + r1) * K + c1 * 8;

    unsigned short* L    = &lds[0][0][0][0];
    unsigned short* dst0 = L + (size_t)g0 * 8;
    unsigned short* dst1 = L + (size_t)g1 * 8;

    auto stage = [&](const unsigned short* s0, const unsigned short* s1, int regOff) {
        __builtin_amdgcn_global_load_lds(
            (const __attribute__((address_space(1))) void*)s0,
            (__attribute__((address_space(3))) void*)(dst0 + regOff), 16, 0, 0);
        __builtin_amdgcn_global_load_lds(
            (const __attribute__((address_space(1))) void*)s1,
            (__attribute__((address_space(3))) void*)(dst1 + regOff), 16, 0, 0);
    };

    // ---- prologue: Ak0(0),Bk0(0),Ak1(0),Bk1(0),Ak0(1),Bk0(1) ----
    stage(sA0,      sA1,      0);                       // Ak0(0)
    stage(sB0,      sB1,      16384);                   // Bk0(0)
    stage(sA0 + 32, sA1 + 32, 8192);                    // Ak1(0)
    stage(sB0 + 32, sB1 + 32, 16384 + 8192);            // Bk1(0)
    stage(sA0 + 64, sA1 + 64, 32768);                   // Ak0(1)
    stage(sB0 + 64, sB1 + 64, 32768 + 16384);           // Bk0(1)
    asm volatile("s_waitcnt vmcnt(8)" ::: "memory");    // tile-0 k0 halves done
    __builtin_amdgcn_sched_barrier(0);
    __builtin_amdgcn_s_barrier();
    __builtin_amdgcn_sched_barrier(0);

    floatx4 acc[8][4] = {};
    const int rowA = wm * 128 + l16;
    const int rowB = wn * 64  + l16;

#pragma unroll 2
    for (int t = 0; t < NT; ++t) {
        const int buf  = (t & 1) * 32768;
        const int bufN = buf ^ 32768;
        const unsigned short* A0 = L + buf;
        const unsigned short* A1 = L + buf + 8192;
        const unsigned short* B0 = L + buf + 16384;
        const unsigned short* B1 = L + buf + 16384 + 8192;
        const bool s01    = (t + 1 < NT);
        const bool s23    = (t + 2 < NT);
        const bool steady = (t < NT - 2);
        const int  k1 = (t + 1) * 64 + 32;   // kh1 of tile t+1
        const int  k2 = (t + 2) * 64;        // kh0 of tile t+2

        bf16x8 af[4], bf[4];

        // ---------- phase 0: m-frags 0..3, kstep 0 ----------
#pragma unroll
        for (int j = 0; j < 4; ++j) bf[j] = *(const bf16x8*)(B0 + (rowB + j * 16) * 32 + cOff);
#pragma unroll
        for (int i = 0; i < 4; ++i) af[i] = *(const bf16x8*)(A0 + (rowA + i * 16) * 32 + cOff);
        if (s01) stage(sA0 + k1, sA1 + k1, bufN + 8192);            // Ak1(t+1)
        asm volatile("s_waitcnt lgkmcnt(0)" ::: "memory");
        __builtin_amdgcn_sched_barrier(0);
        __builtin_amdgcn_s_setprio(1);
#pragma unroll
        for (int i = 0; i < 4; ++i)
#pragma unroll
            for (int j = 0; j < 4; ++j)
                acc[i][j] = __builtin_amdgcn_mfma_f32_16x16x32_bf16(af[i], bf[j], acc[i][j], 0, 0, 0);
        __builtin_amdgcn_s_setprio(0);

        // ---------- phase 1: m-frags 4..7, kstep 0 ----------
#pragma unroll
        for (int i = 0; i < 4; ++i) af[i] = *(const bf16x8*)(A0 + (rowA + 64 + i * 16) * 32 + cOff);
        if (s01) stage(sB0 + k1, sB1 + k1, bufN + 16384 + 8192);    // Bk1(t+1)
        asm volatile("s_waitcnt lgkmcnt(0)" ::: "memory");
        __builtin_amdgcn_sched_barrier(0);
        __builtin_amdgcn_s_setprio(1);
#pragma unroll
        for (int i = 0; i < 4; ++i)
#pragma unroll
            for (int j = 0; j < 4; ++j)
                acc[4 + i][j] = __builtin_amdgcn_mfma_f32_16x16x32_bf16(af[i], bf[j], acc[4 + i][j], 0, 0, 0);
        __builtin_amdgcn_s_setprio(0);
        // ---- gate G1: retire Ak1(t),Bk1(t) for p2/p3 ----
        if (steady) { asm volatile("s_waitcnt vmcnt(8)" ::: "memory"); }
        else        { asm volatile("s_waitcnt vmcnt(0)" ::: "memory"); }
        __builtin_amdgcn_sched_barrier(0);
        __builtin_amdgcn_s_barrier();
        __builtin_amdgcn_sched_barrier(0);

        // ---------- phase 2: m-frags 0..3, kstep 1 ----------
#pragma unroll
        for (int j = 0; j < 4; ++j) bf[j] = *(const bf16x8*)(B1 + (rowB + j * 16) * 32 + cOff);
#pragma unroll
        for (int i = 0; i < 4; ++i) af[i] = *(const bf16x8*)(A1 + (rowA + i * 16) * 32 + cOff);
        if (s23) stage(sA0 + k2, sA1 + k2, buf);                    // Ak0(t+2)
        asm volatile("s_waitcnt lgkmcnt(0)" ::: "memory");
        __builtin_amdgcn_sched_barrier(0);
        __builtin_amdgcn_s_setprio(1);
#pragma unroll
        for (int i = 0; i < 4; ++i)
#pragma unroll
            for (int j = 0; j < 4; ++j)
                acc[i][j] = __builtin_amdgcn_mfma_f32_16x16x32_bf16(af[i], bf[j], acc[i][j], 0, 0, 0);
        __builtin_amdgcn_s_setprio(0);

        // ---------- phase 3: m-frags 4..7, kstep 1 ----------
#pragma unroll
        for (int i = 0; i < 4; ++i) af[i] = *(const bf16x8*)(A1 + (rowA + 64 + i * 16) * 32 + cOff);
        if (s23) stage(sB0 + k2, sB1 + k2, buf + 16384);            // Bk0(t+2)
        asm volatile("s_waitcnt lgkmcnt(0)" ::: "memory");
        __builtin_amdgcn_sched_barrier(0);
        __builtin_amdgcn_s_setprio(1);
#pragma unroll
        for (int i = 0; i < 4; ++i)
#pragma unroll
            for (int j = 0; j < 4; ++j)
                acc[4 + i][j] = __builtin_amdgcn_mfma_f32_16x16x32_bf16(af[i], bf[j], acc[4 + i][j], 0, 0, 0);
        __builtin_amdgcn_s_setprio(0);
        // ---- gate G2: retire Ak0(t+1),Bk0(t+1) for next tile ----
        if (steady) { asm volatile("s_waitcnt vmcnt(8)" ::: "memory"); }
        else        { asm volatile("s_waitcnt vmcnt(0)" ::: "memory"); }
        __builtin_amdgcn_sched_barrier(0);
        __builtin_amdgcn_s_barrier();
        __builtin_amdgcn_sched_barrier(0);
    }

    // ---------------- epilogue: bias + store ----------------
    float bv[4];
#pragma unroll
    for (int j = 0; j < 4; ++j)
        bv[j] = bias[bn * 256 + wn * 64 + j * 16 + l16];

#pragma unroll
    for (int f = 0; f < 8; ++f) {
        int gm = bm * 256 + wm * 128 + f * 16 + q * 4;   // C row = quad*4 + reg
#pragma unroll
        for (int j = 0; j < 4; ++j) {
            int gn = bn * 256 + wn * 64 + j * 16 + l16;  // C col = lane&15
            float* cp = C + (size_t)gm * D_OUT + gn;
#pragma unroll
            for (int r = 0; r < 4; ++r)
                cp[(size_t)r * D_OUT] = acc[f][j][r] + bv[j];
        }
    }
}

extern "C" void kernel_launch(void* const* d_in, const int* in_sizes, int n_in,
                              void* d_out, int out_size, void* d_ws, size_t ws_size,
                              hipStream_t stream) {
    const float* x   = (const float*)d_in[0];
    const float* wgt = (const float*)d_in[1];
    const float* bia = (const float*)d_in[2];
    const float* ls  = (const float*)d_in[3];
    float* out = (float*)d_out;

    char* ws = (char*)d_ws;
    float*          scale = (float*)ws;                                   // 16 KB
    float*          rinv  = (float*)(ws + (16 << 10));                    // 16 KB
    __hip_bfloat16* xq    = (__hip_bfloat16*)(ws + (64 << 10));           // 64 MB
    __hip_bfloat16* wq    = (__hip_bfloat16*)(ws + (64 << 10) + ((size_t)64 << 20)); // 32 MB

    scale_kernel<<<(D_IN + 255) / 256, 256, 0, stream>>>(ls, scale, rinv);
    act_quant<<<M_TOK, 256, 0, stream>>>(x, rinv, xq);
    w_quant<<<(D_OUT * D_IN / 256) / 4, 256, 0, stream>>>(wgt, scale, wq);

    dim3 grid(D_OUT / 256, M_TOK / 256);
    gemm_bt<<<grid, 512, 0, stream>>>(xq, wq, bia, out);
}